// Round 13
// baseline (124.989 us; speedup 1.0000x reference)
//
#include <hip/hip_runtime.h>
#include <hip/hip_bf16.h>
#include <math.h>

#define D_MODEL 1024
#define C_DIM   128
#define BATCH   4
#define SEQ     2048
#define BS_ROWS (BATCH*SEQ)

typedef float  f32x4 __attribute__((ext_vector_type(4)));
typedef short  s16x8 __attribute__((ext_vector_type(8)));
typedef unsigned short u16;
typedef unsigned short u16x4 __attribute__((ext_vector_type(4)));

__device__ inline u16 f2bf(float f){
    unsigned u = __builtin_bit_cast(unsigned, f);
    u += 0x7FFF + ((u >> 16) & 1);          // round-to-nearest-even
    return (u16)(u >> 16);
}

// async global->LDS, 16B per lane; LDS dest = wave-uniform base + lane*16
__device__ inline void gl_lds16(const u16* g, u16* l){
    __builtin_amdgcn_global_load_lds(
        (const __attribute__((address_space(1))) void*)g,
        (__attribute__((address_space(3))) void*)l,
        16, 0, 0);
}

// counted vmem wait: wait until <= N vmem instrs outstanding (this wave)
template<int N> __device__ inline void wait_vm(){
    if constexpr (N <= 0)       asm volatile("s_waitcnt vmcnt(0)"  ::: "memory");
    else if constexpr (N == 4)  asm volatile("s_waitcnt vmcnt(4)"  ::: "memory");
    else if constexpr (N == 6)  asm volatile("s_waitcnt vmcnt(6)"  ::: "memory");
    else if constexpr (N == 8)  asm volatile("s_waitcnt vmcnt(8)"  ::: "memory");
    else if constexpr (N == 12) asm volatile("s_waitcnt vmcnt(12)" ::: "memory");
    else                        asm volatile("s_waitcnt vmcnt(0)"  ::: "memory");
}

// ---------------------------------------------------------------------------
// gemm_deep: C[M,N] = A[M,K] @ BT[N,K]^T — the two big GEMMs.
// 256x128 tile, BK=64, 8 waves (4Mx2N; per-wave 64x64 = identical frag code
// to the verified 4-wave kernel). TRIPLE static-disjoint LDS buffers
// (3 x 48KB), depth-2 staging: phase(t) issues tile t+2, then
// s_waitcnt vmcnt(12) retires exactly tile t (t+1,t+2 stay in flight) ->
// raw barrier -> MFMA -> raw barrier. Latency tolerance = 2 compute phases
// (~700cy) vs depth-1's ~310cy (the 14-16% MfmaUtil wall of rounds 4-12).
// Grid = exactly 256 blocks = 1/CU (8 waves = 2/SIMD keeps TLP), XCD swizzle.
// Flags: OUT_BF16; CK (causal K-extent, BM granularity); RSCALE (/rowsum).
// ORD as in gemm_bt. nkt >= 4 and divisible by 4 for every instantiation.
// ---------------------------------------------------------------------------
template<int OUT_BF16, int CK, int RSCALE, int ORD>
__launch_bounds__(512)
__global__ void gemm_deep(const u16* __restrict__ Ag, const u16* __restrict__ Bg,
                          void* __restrict__ Cg, const float* __restrict__ rowsum,
                          int gx, int gy,
                          int K, int lda, int ldb, int ldc,
                          long sA, long sB, long sC)
{
    constexpr int BM = 256, BN = 128;
    constexpr int WN = 2;
    constexpr int PM = 64, PN = 64, FM = 4, FN = 4;
    constexpr int CA = 4, CB = 2;           // 1KB chunks per wave per stage
    constexpr int ASZ = BM * 64, BSZ = BN * 64;
    __shared__ u16 As0[ASZ]; __shared__ u16 As1[ASZ]; __shared__ u16 As2[ASZ];
    __shared__ u16 Bs0[BSZ]; __shared__ u16 Bs1[BSZ]; __shared__ u16 Bs2[BSZ];

    // XCD-chunked bijective swizzle (nwg % 8 == 0)
    const int nwg = gridDim.x;
    const int l   = (blockIdx.x & 7) * (nwg >> 3) + (blockIdx.x >> 3);
    int mt, nt, z;
    if (ORD == 0) { mt = l % gx; const int r = l / gx; nt = r % gy; z = r / gy; }
    else          { nt = l % gy; const int r = l / gy; mt = r % gx; z = r / gx; }
    const u16* Aa = Ag + (long)z * sA;
    const u16* Bb = Bg + (long)z * sB;
    const int tid = threadIdx.x, lane = tid & 63, wave = tid >> 6;
    const int wr = wave / WN, wc = wave % WN;
    const int mbase = mt * BM, nbase = nt * BN;
    int Keff = K;
    if (CK) { int ke = (mt + 1) * BM; Keff = ke < K ? ke : K; }
    const int nkt = Keff >> 6;              // >= 4

    f32x4 acc[FM][FN];
    #pragma unroll
    for (int m = 0; m < FM; ++m)
        #pragma unroll
        for (int n = 0; n < FN; ++n) acc[m][n] = (f32x4){0.f,0.f,0.f,0.f};

    const int sr  = lane >> 3;
    const int sc8 = (lane & 7) ^ sr;        // XOR-swizzled 16B col slot

    // hoisted staging pointers, advanced 64 elems per STAGE
    const u16* aptr[CA];
    const u16* bptr[CB];
    #pragma unroll
    for (int s = 0; s < CA; ++s)
        aptr[s] = Aa + (size_t)(mbase + (wave * CA + s) * 8 + sr) * lda + sc8 * 8;
    #pragma unroll
    for (int s = 0; s < CB; ++s)
        bptr[s] = Bb + (size_t)(nbase + (wave * CB + s) * 8 + sr) * ldb + sc8 * 8;

    auto STAGE = [&](u16 (&Ad)[ASZ], u16 (&Bd)[BSZ]) {
        #pragma unroll
        for (int s = 0; s < CA; ++s) { gl_lds16(aptr[s], &Ad[(wave * CA + s) * 512]); aptr[s] += 64; }
        #pragma unroll
        for (int s = 0; s < CB; ++s) { gl_lds16(bptr[s], &Bd[(wave * CB + s) * 512]); bptr[s] += 64; }
    };

    auto COMPUTE = [&](const u16 (&Ap)[ASZ], const u16 (&Bp)[BSZ]) {
        #pragma unroll
        for (int ks = 0; ks < 2; ++ks) {
            s16x8 af[FM], bfr[FN];
            const int k8 = ks * 4 + (lane >> 4);
            #pragma unroll
            for (int m = 0; m < FM; ++m) {
                const int row = wr * PM + m * 16 + (lane & 15);
                af[m] = *(const s16x8*)&Ap[row * 64 + ((k8 ^ (row & 7)) << 3)];
            }
            #pragma unroll
            for (int n = 0; n < FN; ++n) {
                const int row = wc * PN + n * 16 + (lane & 15);
                bfr[n] = *(const s16x8*)&Bp[row * 64 + ((k8 ^ (row & 7)) << 3)];
            }
            #pragma unroll
            for (int m = 0; m < FM; ++m)
                #pragma unroll
                for (int n = 0; n < FN; ++n)
                    acc[m][n] = __builtin_amdgcn_mfma_f32_16x16x32_bf16(af[m], bfr[n], acc[m][n], 0, 0, 0);
        }
    };

    // phase(t): stage t+2, retire t (leave t+1,t+2 in flight), compute t
    auto PHASE = [&](u16 (&Ac)[ASZ], u16 (&Bc)[BSZ],
                     u16 (&An)[ASZ], u16 (&Bn)[BSZ], int t) {
        if (t + 2 < nkt) STAGE(An, Bn);
        const int ah = nkt - 1 - t;
        if (ah >= 2)      wait_vm<12>();
        else if (ah == 1) wait_vm<6>();
        else              wait_vm<0>();
        __builtin_amdgcn_s_barrier();
        COMPUTE(Ac, Bc);
        __builtin_amdgcn_s_barrier();
    };

    // prologue: tiles 0,1 into buffers 0,1
    STAGE(As0, Bs0);
    STAGE(As1, Bs1);
    for (int t = 0; t < nkt; t += 3) {
        PHASE(As0, Bs0, As2, Bs2, t);
        if (t + 1 >= nkt) break;
        PHASE(As1, Bs1, As0, Bs0, t + 1);
        if (t + 2 >= nkt) break;
        PHASE(As2, Bs2, As1, Bs1, t + 2);
    }

    // epilogue: C/D layout col=lane&15, row=(lane>>4)*4+r (m89-verified)
    const int lr = (lane >> 4) * 4, lc = lane & 15;
    #pragma unroll
    for (int m = 0; m < FM; ++m) {
        #pragma unroll
        for (int n = 0; n < FN; ++n) {
            const int gr = mbase + wr * PM + m * 16 + lr;
            const int gc = nbase + wc * PN + n * 16 + lc;
            #pragma unroll
            for (int r = 0; r < 4; ++r) {
                float f = acc[m][n][r];
                if (RSCALE) f /= rowsum[(long)z * SEQ + gr + r];
                const size_t off = (size_t)(gr + r) * ldc + gc;
                if (OUT_BF16) ((u16*)Cg + (long)z * sC)[off] = f2bf(f);
                else          ((float*)Cg + (long)z * sC)[off] = f;
            }
        }
    }
}

// ---------------------------------------------------------------------------
// gemm_bt (round-12, verified): qk projection + scores kernels.
// ---------------------------------------------------------------------------
template<int BM, int BN, int WM, int WN, int OUT_BF16, int MASK, int CSKIP,
         int CK, int QKF, int EXPSUM, int RSCALE, int ORD>
__launch_bounds__(WM*WN*64)
__global__ void gemm_bt(const u16* __restrict__ Ag, const u16* __restrict__ Bg,
                        const u16* __restrict__ Bg2,
                        void* __restrict__ Cg, void* __restrict__ Cg2,
                        const float* __restrict__ maskp,
                        float* __restrict__ rowsum,
                        int gx, int gy,
                        int K, int lda, int ldb, int ldc,
                        long sA, long sB, long sC, float scale)
{
    constexpr int W  = WM * WN;
    constexpr int PM = BM / WM, PN = BN / WN;
    constexpr int FM = PM / 16, FN = PN / 16;
    constexpr int CA = BM / 8 / W;
    constexpr int CB = BN / 8 / W;
    constexpr int NL = CA + CB;
    constexpr int ASZ = BM * 64, BSZ = BN * 64;
    __shared__ u16 As0[ASZ];
    __shared__ u16 As1[ASZ];
    __shared__ u16 Bs0[BSZ];
    __shared__ u16 Bs1[BSZ];

    const int nwg = gridDim.x;
    const int l   = (blockIdx.x & 7) * (nwg >> 3) + (blockIdx.x >> 3);
    int mt, nt, z, path = 0;
    if (ORD == 0) { mt = l % gx; const int r = l / gx; nt = r % gy; z = r / gy; }
    else          { nt = l % gy; const int r = l / gy; mt = r % gx; z = r / gx; }
    if (QKF) { constexpr int NT = C_DIM / BN; path = nt / NT; nt = nt % NT; }
    if (CSKIP && nt * BN >= (mt + 1) * BM) return;
    const u16* Aa = Ag + (long)z * sA;
    const u16* Bb = ((QKF && path) ? Bg2 : Bg) + (long)z * sB;
    const int tid = threadIdx.x, lane = tid & 63, wave = tid >> 6;
    const int wr = wave / WN, wc = wave % WN;
    const int mbase = mt * BM, nbase = nt * BN;
    int Keff = K;
    if (CK) { int ke = (mt + 1) * BM; Keff = ke < K ? ke : K; }
    const int nkt = Keff >> 6;

    f32x4 acc[FM][FN];
    #pragma unroll
    for (int m = 0; m < FM; ++m)
        #pragma unroll
        for (int n = 0; n < FN; ++n) acc[m][n] = (f32x4){0.f,0.f,0.f,0.f};

    const int sr  = lane >> 3;
    const int sc8 = (lane & 7) ^ sr;

    const u16* aptr[CA];
    const u16* bptr[CB];
    #pragma unroll
    for (int s = 0; s < CA; ++s)
        aptr[s] = Aa + (size_t)(mbase + (wave * CA + s) * 8 + sr) * lda + sc8 * 8;
    #pragma unroll
    for (int s = 0; s < CB; ++s)
        bptr[s] = Bb + (size_t)(nbase + (wave * CB + s) * 8 + sr) * ldb + sc8 * 8;

    auto STAGE = [&](u16 (&Ad)[ASZ], u16 (&Bd)[BSZ]) {
        #pragma unroll
        for (int s = 0; s < CA; ++s) { gl_lds16(aptr[s], &Ad[(wave * CA + s) * 512]); aptr[s] += 64; }
        #pragma unroll
        for (int s = 0; s < CB; ++s) { gl_lds16(bptr[s], &Bd[(wave * CB + s) * 512]); bptr[s] += 64; }
    };

    auto COMPUTE = [&](const u16 (&Ap)[ASZ], const u16 (&Bp)[BSZ]) {
        #pragma unroll
        for (int ks = 0; ks < 2; ++ks) {
            s16x8 af[FM], bfr[FN];
            const int k8 = ks * 4 + (lane >> 4);
            #pragma unroll
            for (int m = 0; m < FM; ++m) {
                const int row = wr * PM + m * 16 + (lane & 15);
                af[m] = *(const s16x8*)&Ap[row * 64 + ((k8 ^ (row & 7)) << 3)];
            }
            #pragma unroll
            for (int n = 0; n < FN; ++n) {
                const int row = wc * PN + n * 16 + (lane & 15);
                bfr[n] = *(const s16x8*)&Bp[row * 64 + ((k8 ^ (row & 7)) << 3)];
            }
            #pragma unroll
            for (int m = 0; m < FM; ++m)
                #pragma unroll
                for (int n = 0; n < FN; ++n)
                    acc[m][n] = __builtin_amdgcn_mfma_f32_16x16x32_bf16(af[m], bfr[n], acc[m][n], 0, 0, 0);
        }
    };

    STAGE(As0, Bs0);
    for (int t = 0; t < nkt; t += 2) {
        STAGE(As1, Bs1);
        wait_vm<NL>();
        __builtin_amdgcn_s_barrier();
        COMPUTE(As0, Bs0);
        __builtin_amdgcn_s_barrier();
        if (t + 2 < nkt) { STAGE(As0, Bs0); wait_vm<NL>(); }
        else             { wait_vm<0>(); }
        __builtin_amdgcn_s_barrier();
        COMPUTE(As1, Bs1);
        __builtin_amdgcn_s_barrier();
    }

    const bool kpath = QKF && path;
    void* Cout = kpath ? Cg2 : Cg;
    const int lr = (lane >> 4) * 4, lc = lane & 15;
    float rs[FM][4];
    if (EXPSUM) {
        #pragma unroll
        for (int m = 0; m < FM; ++m)
            #pragma unroll
            for (int r = 0; r < 4; ++r) rs[m][r] = 0.f;
    }
    #pragma unroll
    for (int m = 0; m < FM; ++m) {
        #pragma unroll
        for (int n = 0; n < FN; ++n) {
            const int gr = mbase + wr * PM + m * 16 + lr;
            const int gc = nbase + wc * PN + n * 16 + lc;
            #pragma unroll
            for (int r = 0; r < 4; ++r) {
                float f = acc[m][n][r] * scale;
                if (EXPSUM) {
                    f = (gc <= gr + r) ? __expf(f) : 0.f;
                    rs[m][r] += f;
                }
                if (RSCALE) f /= rowsum[(long)z * SEQ + gr + r];
                const size_t off = (size_t)(gr + r) * ldc + gc;
                if (MASK) { if (!kpath) f *= maskp[(long)z * sC + off]; }
                if (OUT_BF16) ((u16*)Cout + (long)z * sC)[off] = f2bf(f);
                else          ((float*)Cout + (long)z * sC)[off] = f;
            }
        }
    }
    if (EXPSUM) {
        #pragma unroll
        for (int m = 0; m < FM; ++m) {
            #pragma unroll
            for (int r = 0; r < 4; ++r) {
                float v = rs[m][r];
                v += __shfl_xor(v, 1); v += __shfl_xor(v, 2);
                v += __shfl_xor(v, 4); v += __shfl_xor(v, 8);
                if ((lane & 15) == 0) {
                    const int gr = mbase + wr * PM + m * 16 + lr + r;
                    atomicAdd(rowsum + (long)z * SEQ + gr, v);
                }
            }
        }
    }
}

// ---------------------------------------------------------------------------
__launch_bounds__(256)
__global__ void transpose_cvt(const float* __restrict__ in, u16* __restrict__ out,
                              int R, int Cc)
{
    __shared__ float t[32][33];
    const int c0 = blockIdx.x * 32, r0 = blockIdx.y * 32;
    const int tx = threadIdx.x & 31, ty = threadIdx.x >> 5;
    #pragma unroll
    for (int i = 0; i < 32; i += 8) t[ty + i][tx] = in[(size_t)(r0 + ty + i) * Cc + c0 + tx];
    __syncthreads();
    #pragma unroll
    for (int i = 0; i < 32; i += 8) out[(size_t)(c0 + ty + i) * R + r0 + tx] = f2bf(t[tx][ty + i]);
}

__launch_bounds__(256)
__global__ void convert_cvt(const float* __restrict__ in, u16* __restrict__ out, int n4)
{
    for (int i = blockIdx.x * 256 + threadIdx.x; i < n4; i += gridDim.x * 256) {
        float4 f = reinterpret_cast<const float4*>(in)[i];
        u16x4 o = { f2bf(f.x), f2bf(f.y), f2bf(f.z), f2bf(f.w) };
        reinterpret_cast<u16x4*>(out)[i] = o;
    }
}

// ---------------------------------------------------------------------------
extern "C" void kernel_launch(void* const* d_in, const int* in_sizes, int n_in,
                              void* d_out, int out_size, void* d_ws, size_t ws_size,
                              hipStream_t stream)
{
    const float* x    = (const float*)d_in[0];
    const float* A    = (const float*)d_in[1];
    const float* Bm   = (const float*)d_in[2];
    const float* ov   = (const float*)d_in[3];
    const float* mask = (const float*)d_in[4];

    // workspace layout: ~70.3 MiB
    char* w = (char*)d_ws;
    u16* xb   = (u16*)w; w += (size_t)BS_ROWS * D_MODEL * 2;   // x bf16 row-major
    u16* AbT  = (u16*)w; w += (size_t)C_DIM * D_MODEL * 2;     // A^T [C][D]
    u16* Bmb  = (u16*)w; w += (size_t)C_DIM * D_MODEL * 2;     // Bmat [C][D]
    u16* ovT  = (u16*)w; w += (size_t)D_MODEL * D_MODEL * 2;   // ov^T [e][d]
    u16* qm   = (u16*)w; w += (size_t)BS_ROWS * C_DIM * 2;     // masked q
    u16* kk   = (u16*)w; w += (size_t)BS_ROWS * C_DIM * 2;     // k
    u16* sc   = (u16*)w; w += (size_t)BATCH * SEQ * SEQ * 2;   // Pu = exp(scores)
    u16* xovT = (u16*)w; w += (size_t)D_MODEL * BS_ROWS * 2;   // (x@ov)^T [e][k]
    float* rowsum = (float*)w; w += (size_t)BS_ROWS * 4;       // softmax denoms

    hipMemsetAsync(rowsum, 0, (size_t)BS_ROWS * 4, stream);

    // prep
    convert_cvt<<<2048, 256, 0, stream>>>(x, xb, BS_ROWS * D_MODEL / 4);
    convert_cvt<<<128, 256, 0, stream>>>(Bm, Bmb, C_DIM * D_MODEL / 4);
    transpose_cvt<<<dim3(D_MODEL/32, D_MODEL/32, 1), 256, 0, stream>>>(ov, ovT, D_MODEL, D_MODEL);
    transpose_cvt<<<dim3(C_DIM/32, D_MODEL/32, 1), 256, 0, stream>>>(A, AbT, D_MODEL, C_DIM);

    // xovT[e][k] = ovT @ xb^T   (M=1024, N=8192, K=1024)
    // deep pipeline: 256x128, 8 waves, 256 blocks (1/CU), nkt=16
    gemm_deep<1,0,0, 0><<<256, 512, 0, stream>>>(
        ovT, xb, xovT, nullptr,
        /*gx*/4, /*gy*/64,
        D_MODEL, D_MODEL, D_MODEL, BS_ROWS, 0, 0, 0);

    // fused q & k projection: 64x64 tiles, 4 waves; 512 blocks; ORD=1
    gemm_bt<64,64,2,2, 1,1,0,0,1,0,0, 1><<<512, 256, 0, stream>>>(
        xb, AbT, Bmb, qm, kk, mask, nullptr,
        /*gx*/128, /*gy*/4,
        D_MODEL, D_MODEL, D_MODEL, C_DIM, 0, 0, 0, 1.0f);

    // Pu = exp(qm @ kk^T / D) causal-zeroed (+ rowsum atomics); 1024 blocks
    gemm_bt<128,128,2,2, 1,0,1,0,0,1,0, 1><<<1024, 256, 0, stream>>>(
        qm, kk, nullptr, sc, nullptr, nullptr, rowsum,
        /*gx*/16, /*gy*/16,
        C_DIM, C_DIM, C_DIM, SEQ,
        (long)SEQ * C_DIM, (long)SEQ * C_DIM, (long)SEQ * SEQ, 1.0f / D_MODEL);

    // out = (Pu @ xovT^T) / rowsum   (per batch, causal K-extent, fp32 out)
    // deep pipeline: 256x128, 8 waves, 256 blocks (1/CU), nkt=(mt+1)*4
    gemm_deep<0,1,1, 0><<<256, 512, 0, stream>>>(
        sc, xovT, d_out, rowsum,
        /*gx*/8, /*gy*/8,
        SEQ, SEQ, BS_ROWS, D_MODEL,
        (long)SEQ * SEQ, (long)SEQ, (long)SEQ * D_MODEL);
}